// Round 3
// baseline (767.226 us; speedup 1.0000x reference)
//
#include <hip/hip_runtime.h>
#include <hip/hip_bf16.h>
#include <math.h>

#define SEQ 2048
#define DIM 2048
#define NHEAD 16
#define HD 128
#define HIDDEN 5632
#define QKVN 6144
#define NCHUNK_TOT 80   // sum_{it=0}^{31} (it/8 + 1)
constexpr float EPS = 1e-6f;

typedef __hip_bfloat16 bf16;
using short8  = __attribute__((ext_vector_type(8))) short;
using short4v = __attribute__((ext_vector_type(4))) short;
using floatx4 = __attribute__((ext_vector_type(4))) float;

__device__ inline void gl_lds16(const void* g, void* l) {
    __builtin_amdgcn_global_load_lds((const __attribute__((address_space(1))) void*)g,
                                     (__attribute__((address_space(3))) void*)l, 16, 0, 0);
}

__device__ inline short bfbits(float f) {
    bf16 b = __float2bfloat16(f);
    return *(const short*)&b;
}

// ---------------------------------------------------------------- rmsnorm (f32 in, bf16 out)
__global__ __launch_bounds__(256) void rmsnorm_kernel(const float* __restrict__ x,
                                                      const float* __restrict__ g,
                                                      bf16* __restrict__ out) {
    int row = blockIdx.x;
    const float4* xr = (const float4*)(x + (size_t)row * DIM);
    const float4* g4 = (const float4*)g;
    float4 v[2];
    float ss = 0.f;
#pragma unroll
    for (int i = 0; i < 2; ++i) {
        v[i] = xr[threadIdx.x + 256 * i];
        ss += v[i].x * v[i].x + v[i].y * v[i].y + v[i].z * v[i].z + v[i].w * v[i].w;
    }
    __shared__ float red[256];
    red[threadIdx.x] = ss;
    __syncthreads();
    for (int s = 128; s > 0; s >>= 1) {
        if (threadIdx.x < s) red[threadIdx.x] += red[threadIdx.x + s];
        __syncthreads();
    }
    float scale = rsqrtf(red[0] / (float)DIM + EPS);
    bf16* orow = out + (size_t)row * DIM;
#pragma unroll
    for (int i = 0; i < 2; ++i) {
        float4 gv = g4[threadIdx.x + 256 * i];
        short4v o;
        o[0] = bfbits(v[i].x * scale * gv.x);
        o[1] = bfbits(v[i].y * scale * gv.y);
        o[2] = bfbits(v[i].z * scale * gv.z);
        o[3] = bfbits(v[i].w * scale * gv.w);
        *(short4v*)&orow[(threadIdx.x + 256 * i) * 4] = o;
    }
}

// ---------------------------------------------------------------- weight cast+transpose
// in: [K][N] f32, out: [N][K] bf16.  64x64 tile, float4 loads, 4x4 register
// transpose -> LDS [n][k], short8 (16B) stores.
__global__ __launch_bounds__(256) void cvt_t_kernel(const float* __restrict__ in,
                                                    bf16* __restrict__ out,
                                                    int K, int N) {
    __shared__ bf16 L[64][72];
    const int nb = blockIdx.x * 64, kb = blockIdx.y * 64;
    const int t = threadIdx.x;
    const int nq = t & 15;   // n group of 4
    const int kq = t >> 4;   // k group of 4
    float4 v[4];
#pragma unroll
    for (int i = 0; i < 4; ++i)
        v[i] = *(const float4*)&in[(size_t)(kb + kq * 4 + i) * N + nb + nq * 4];
#pragma unroll
    for (int j = 0; j < 4; ++j) {
        short4v o;
#pragma unroll
        for (int i = 0; i < 4; ++i)
            o[i] = bfbits(((const float*)&v[i])[j]);
        *(short4v*)&L[nq * 4 + j][kq * 4] = o;
    }
    __syncthreads();
    const int c8 = t & 7, rw = t >> 3;
#pragma unroll
    for (int p = 0; p < 2; ++p) {
        int row = rw + p * 32;
        *(short8*)&out[(size_t)(nb + row) * K + kb + c8 * 8] = *(const short8*)&L[row][c8 * 8];
    }
}

// ---------------------------------------------------------------- bf16 MFMA GEMM
// m97 fragment layout + depth-3 counted-vmcnt pipeline (T4): 3 LDS buffers,
// loads kept TWO K-tiles in flight, raw s_barrier with hand-counted
// s_waitcnt vmcnt(8/4/0) — never a full drain in the main loop. Per iter:
//   stage(i+2) -> vmcnt(8) -> barrier -> ds_read+MFMA -> lgkmcnt(0) -> barrier
// WAR: stage(i+2) reuses the buffer read at iter i-1 (protected by the
// loop-end barrier); RAW: every wave passes its own vmcnt(8) before barrier A.
// LDS 48 KB -> 3 blocks/CU. Bijective XCD swizzle (m204) for L2 panel reuse.
template <int MODE>
__global__ __launch_bounds__(256) void gemm_bf16(const bf16* __restrict__ A,
                                                 const bf16* __restrict__ Bt,
                                                 void* __restrict__ Cv,
                                                 const float* __restrict__ R,
                                                 int K, int ldc) {
    __shared__ bf16 Asm[3][128 * 32];
    __shared__ bf16 Bsm[3][128 * 32];
    const int t = threadIdx.x;

    // XCD-aware bijective block swizzle
    int wg = blockIdx.y * gridDim.x + blockIdx.x;
    {
        const int nwg = gridDim.x * gridDim.y;
        const int q = nwg >> 3, r = nwg & 7;
        const int xcd = wg & 7, loc = wg >> 3;
        wg = (xcd < r ? xcd * (q + 1) : r * (q + 1) + (xcd - r) * q) + loc;
    }
    const int m0 = (wg / gridDim.x) * 128;
    const int n0 = (wg % gridDim.x) * 128;

    const int lane = t & 63;
    const int wave = t >> 6;
    const int wr = wave >> 1, wc = wave & 1;
    const int quad = lane >> 4;
    const int l16 = lane & 15;

    floatx4 acc[4][4] = {};

    const int ar = t >> 2;
    const int ak = (t & 3) * 8;
    const bf16* Ag = A + (size_t)(m0 + ar) * K + ak;
    const bf16* Bg = Bt + (size_t)(n0 + ar) * K + ak;
    const size_t half = (size_t)64 * K;
    const int NT = K >> 5;

    auto stage = [&](int tile, int buf) {
        const bf16* a = Ag + tile * 32;
        const bf16* b = Bg + tile * 32;
        gl_lds16(a, Asm[buf] + t * 8);
        gl_lds16(a + half, Asm[buf] + t * 8 + 64 * 32);
        gl_lds16(b, Bsm[buf] + t * 8);
        gl_lds16(b + half, Bsm[buf] + t * 8 + 64 * 32);
    };

    // prologue: two tiles in flight
    stage(0, 0);
    if (NT > 1) stage(1, 1);

    int cb = 0;
    for (int i = 0; i < NT; ++i) {
        if (i + 2 < NT) stage(i + 2, cb == 0 ? 2 : cb - 1);   // (i+2)%3

        if (i + 2 < NT)      asm volatile("s_waitcnt vmcnt(8)" ::: "memory");
        else if (i + 1 < NT) asm volatile("s_waitcnt vmcnt(4)" ::: "memory");
        else                 asm volatile("s_waitcnt vmcnt(0)" ::: "memory");
        __builtin_amdgcn_s_barrier();   // barrier A: tile i fully in LDS

        const bf16* As = Asm[cb];
        const bf16* Bs = Bsm[cb];
        short8 af[4], bfr[4];
#pragma unroll
        for (int i2 = 0; i2 < 4; ++i2)
            af[i2] = *(const short8*)(As + (wr * 64 + i2 * 16 + l16) * 32 + quad * 8);
#pragma unroll
        for (int j = 0; j < 4; ++j)
            bfr[j] = *(const short8*)(Bs + (wc * 64 + j * 16 + l16) * 32 + quad * 8);
#pragma unroll
        for (int i2 = 0; i2 < 4; ++i2)
#pragma unroll
            for (int j = 0; j < 4; ++j)
                acc[i2][j] = __builtin_amdgcn_mfma_f32_16x16x32_bf16(af[i2], bfr[j], acc[i2][j], 0, 0, 0);

        asm volatile("s_waitcnt lgkmcnt(0)" ::: "memory");
        __builtin_amdgcn_s_barrier();   // barrier B: all reads of buf[cb] done
        cb = (cb == 2) ? 0 : cb + 1;
    }

#pragma unroll
    for (int i = 0; i < 4; ++i) {
#pragma unroll
        for (int j = 0; j < 4; ++j) {
#pragma unroll
            for (int r = 0; r < 4; ++r) {
                int m = m0 + wr * 64 + i * 16 + quad * 4 + r;
                int n = n0 + wc * 64 + j * 16 + l16;
                size_t idx = (size_t)m * ldc + n;
                float v = acc[i][j][r];
                if (MODE == 0) {
                    ((bf16*)Cv)[idx] = __float2bfloat16(v);
                } else if (MODE == 1) {
                    ((float*)Cv)[idx] = v + R[idx];
                } else if (MODE == 2) {
                    ((bf16*)Cv)[idx] = __float2bfloat16(v / (1.f + __expf(-v)));
                } else {
                    bf16* C = (bf16*)Cv;
                    C[idx] = __float2bfloat16(__bfloat162float(C[idx]) * v);
                }
            }
        }
    }
}

// ---------------------------------------------------------------- RoPE (in-place, bf16 qkv buffer)
__global__ __launch_bounds__(256) void rope_kernel(bf16* __restrict__ qkv,
                                                   const float* __restrict__ cs,
                                                   const float* __restrict__ sn) {
    int idx = blockIdx.x * 256 + threadIdx.x;
    int d2 = idx % (HD / 2);
    int rest = idx / (HD / 2);
    int h = rest % NHEAD;
    int s = rest / NHEAD;
    float c = cs[s * (HD / 2) + d2];
    float si = sn[s * (HD / 2) + d2];
    bf16* qp = qkv + (size_t)s * QKVN + h * HD + 2 * d2;
    bf16* kp = qp + DIM;
    float qr = __bfloat162float(qp[0]), qi = __bfloat162float(qp[1]);
    qp[0] = __float2bfloat16(qr * c - qi * si);
    qp[1] = __float2bfloat16(qr * si + qi * c);
    float kr = __bfloat162float(kp[0]), ki = __bfloat162float(kp[1]);
    kp[0] = __float2bfloat16(kr * c - ki * si);
    kp[1] = __float2bfloat16(kr * si + ki * c);
}

// ---------------------------------------------------------------- chunked MFMA flash attention
// Grid (80, NHEAD). blockIdx.x decodes to (it = q-tile, c = KV chunk of <=8
// tiles). 1280 uniform blocks; each writes UNNORMALIZED partial O + per-row
// (m, l) in the exp2 domain; attn_combine merges <=4 partials.
__global__ __launch_bounds__(256, 3) void flash_attn_chunk(const bf16* __restrict__ qkv,
                                                           float* __restrict__ Opart,
                                                           float* __restrict__ Mpart) {
    __shared__ bf16 Ks[64][136];    // key-major, pad 8 (stride 272 B)
    __shared__ bf16 Vt[128][72];    // dim-major, pad 8 (stride 144 B)
    __shared__ bf16 Ps[64][72];

    const int h = blockIdx.y;
    int rem = blockIdx.x, it = 0;
    for (;;) { int nc = (it >> 3) + 1; if (rem < nc) break; rem -= nc; ++it; }
    const int c = rem;
    const int q8 = it >> 3, r8 = it & 7;
    const int slot = h * NCHUNK_TOT + (q8 + 1) * (4 * q8 + r8) + c;
    const int j0 = c * 8;
    const int j1 = (j0 + 8 < it + 1) ? (j0 + 8) : (it + 1);

    const int t = threadIdx.x;
    const int lane = t & 63;
    const int w = t >> 6;
    const int quad = lane >> 4;
    const int l16 = lane & 15;
    const int s0 = it * 64;
    // 1/sqrt(128) * log2(e): base-2 softmax
    const float sl2 = (float)(0.08838834764831845 * 1.4426950408889634);

    // ---- Q strip in registers: A-frag layout m=l16, k=quad*8+j
    short8 qreg[4];
    {
        const bf16* qrow = qkv + (size_t)(s0 + 16 * w + l16) * QKVN + h * HD + quad * 8;
#pragma unroll
        for (int ks = 0; ks < 4; ++ks)
            qreg[ks] = *(const short8*)(qrow + ks * 32);
    }

    floatx4 O[8] = {};
    float m_i[4], l_i[4];
#pragma unroll
    for (int r = 0; r < 4; ++r) { m_i[r] = -INFINITY; l_i[r] = 0.f; }

    const int vkg = t >> 5;
    const int vdg = t & 31;

    for (int jt = j0; jt < j1; ++jt) {
        const int tb = jt * 64;
        __syncthreads();

        // ---- stage K tile [64][128], coalesced 16B
#pragma unroll
        for (int u = 0; u < 4; ++u) {
            int vv = t + 256 * u;
            int kr = vv >> 4, kc = vv & 15;
            *(uint4*)&Ks[kr][kc * 8] =
                *(const uint4*)(qkv + (size_t)(tb + kr) * QKVN + DIM + h * HD + kc * 8);
        }
        // ---- stage V transposed via register transpose
        {
            short4v vr[8];
#pragma unroll
            for (int kk = 0; kk < 8; ++kk)
                vr[kk] = *(const short4v*)(qkv + (size_t)(tb + vkg * 8 + kk) * QKVN + 2 * DIM + h * HD + vdg * 4);
#pragma unroll
            for (int dd = 0; dd < 4; ++dd) {
                short8 wv;
#pragma unroll
                for (int kk = 0; kk < 8; ++kk) wv[kk] = vr[kk][dd];
                *(short8*)&Vt[vdg * 4 + dd][vkg * 8] = wv;
            }
        }
        __syncthreads();

        // ---- S = Q K^T : wave strip 16 x 64
        floatx4 sacc[4] = {};
#pragma unroll
        for (int ks = 0; ks < 4; ++ks) {
            short8 kb[4];
#pragma unroll
            for (int nt = 0; nt < 4; ++nt)
                kb[nt] = *(const short8*)&Ks[nt * 16 + l16][ks * 32 + quad * 8];
#pragma unroll
            for (int nt = 0; nt < 4; ++nt)
                sacc[nt] = __builtin_amdgcn_mfma_f32_16x16x32_bf16(qreg[ks], kb[nt], sacc[nt], 0, 0, 0);
        }

        // ---- scale(log2) + causal mask + online softmax, base-2
        float alpha[4];
#pragma unroll
        for (int r = 0; r < 4; ++r) {
            float mx = -INFINITY;
#pragma unroll
            for (int nt = 0; nt < 4; ++nt) {
                float s = sacc[nt][r] * sl2;
                if (jt == it && (nt * 16 + l16) > (16 * w + quad * 4 + r)) s = -INFINITY;
                sacc[nt][r] = s;
                mx = fmaxf(mx, s);
            }
#pragma unroll
            for (int off = 1; off < 16; off <<= 1)
                mx = fmaxf(mx, __shfl_xor(mx, off, 64));
            float mn = fmaxf(m_i[r], mx);
            alpha[r] = exp2f(m_i[r] - mn);
            float lsum = 0.f;
#pragma unroll
            for (int nt = 0; nt < 4; ++nt) {
                float e = exp2f(sacc[nt][r] - mn);
                sacc[nt][r] = e;
                lsum += e;
            }
#pragma unroll
            for (int off = 1; off < 16; off <<= 1)
                lsum += __shfl_xor(lsum, off, 64);
            l_i[r] = l_i[r] * alpha[r] + lsum;
            m_i[r] = mn;
        }

        // ---- P (C-layout) -> LDS, own strip only
#pragma unroll
        for (int nt = 0; nt < 4; ++nt)
#pragma unroll
            for (int r = 0; r < 4; ++r)
                Ps[16 * w + quad * 4 + r][nt * 16 + l16] = __float2bfloat16(sacc[nt][r]);

        // ---- rescale O, then O += P V
#pragma unroll
        for (int nt = 0; nt < 8; ++nt)
#pragma unroll
            for (int r = 0; r < 4; ++r)
                O[nt][r] *= alpha[r];

#pragma unroll
        for (int ks = 0; ks < 2; ++ks) {
            short8 pa = *(const short8*)&Ps[16 * w + l16][ks * 32 + quad * 8];
#pragma unroll
            for (int nt = 0; nt < 8; ++nt) {
                short8 vb = *(const short8*)&Vt[nt * 16 + l16][ks * 32 + quad * 8];
                O[nt] = __builtin_amdgcn_mfma_f32_16x16x32_bf16(pa, vb, O[nt], 0, 0, 0);
            }
        }
    }

    // ---- write UNNORMALIZED partials + (m, l)
    float* Op = Opart + (size_t)slot * (64 * 128);
    float* Mp = Mpart + (size_t)slot * 128;
    if (l16 == 0) {
#pragma unroll
        for (int r = 0; r < 4; ++r) {
            int row = 16 * w + quad * 4 + r;
            Mp[row] = m_i[r];
            Mp[64 + row] = l_i[r];
        }
    }
#pragma unroll
    for (int r = 0; r < 4; ++r) {
        int row = 16 * w + quad * 4 + r;
#pragma unroll
        for (int nt = 0; nt < 8; ++nt)
            Op[row * 128 + nt * 16 + l16] = O[nt][r];
    }
}

// ---------------------------------------------------------------- combine partials -> bf16 out
// Grid (SEQ/64, NHEAD), 256 thr. Thread t: row = t>>2, dim quarter = t&3.
__global__ __launch_bounds__(256) void attn_combine(const float* __restrict__ Opart,
                                                    const float* __restrict__ Mpart,
                                                    bf16* __restrict__ out) {
    const int it = blockIdx.x;
    const int h = blockIdx.y;
    const int nch = (it >> 3) + 1;
    const int q8 = it >> 3, r8 = it & 7;
    const int base = h * NCHUNK_TOT + (q8 + 1) * (4 * q8 + r8);
    const int t = threadIdx.x;
    const int row = t >> 2;
    const int dq = t & 3;

    float mv[4], wgt[4];
    float M = -INFINITY;
#pragma unroll
    for (int c = 0; c < 4; ++c) {
        if (c < nch) {
            mv[c] = Mpart[(size_t)(base + c) * 128 + row];
            M = fmaxf(M, mv[c]);
        }
    }
    float L = 0.f;
#pragma unroll
    for (int c = 0; c < 4; ++c) {
        if (c < nch) {
            wgt[c] = exp2f(mv[c] - M);
            L += Mpart[(size_t)(base + c) * 128 + 64 + row] * wgt[c];
        }
    }
    float inv = 1.f / L;

    float acc[32] = {};
#pragma unroll
    for (int c = 0; c < 4; ++c) {
        if (c < nch) {
            const float* Oc = Opart + ((size_t)(base + c) * 64 + row) * 128 + dq * 32;
            float wc = wgt[c];
#pragma unroll
            for (int k = 0; k < 8; ++k) {
                float4 v = *(const float4*)&Oc[k * 4];
                acc[k * 4 + 0] += wc * v.x;
                acc[k * 4 + 1] += wc * v.y;
                acc[k * 4 + 2] += wc * v.z;
                acc[k * 4 + 3] += wc * v.w;
            }
        }
    }

    bf16* orow = out + (size_t)(it * 64 + row) * DIM + h * HD + dq * 32;
#pragma unroll
    for (int k2 = 0; k2 < 4; ++k2) {
        short8 pk;
#pragma unroll
        for (int e = 0; e < 8; ++e)
            pk[e] = bfbits(acc[k2 * 8 + e] * inv);
        *(short8*)&orow[k2 * 8] = pk;
    }
}

// ---------------------------------------------------------------- launch
extern "C" void kernel_launch(void* const* d_in, const int* in_sizes, int n_in,
                              void* d_out, int out_size, void* d_ws, size_t ws_size,
                              hipStream_t stream) {
    const float* x      = (const float*)d_in[0];
    const float* f_cos  = (const float*)d_in[1];
    const float* f_sin  = (const float*)d_in[2];
    // d_in[3] = mask : ignored (causality analytic)
    const float* wq     = (const float*)d_in[4];
    const float* wk     = (const float*)d_in[5];
    const float* wv     = (const float*)d_in[6];
    const float* wo     = (const float*)d_in[7];
    const float* w1     = (const float*)d_in[8];
    const float* w2     = (const float*)d_in[9];
    const float* w3     = (const float*)d_in[10];
    const float* g_attn = (const float*)d_in[11];
    const float* g_ffn  = (const float*)d_in[12];
    float* out = (float*)d_out;

    char* base = (char*)d_ws;
    size_t off = 0;
    auto alloc = [&](size_t bytes) { void* p = base + off; off += (bytes + 255) & ~255ULL; return p; };
    bf16* qkvt = (bf16*)alloc((size_t)QKVN * DIM * 2);
    bf16* wot  = (bf16*)alloc((size_t)DIM * DIM * 2);
    bf16* w1t  = (bf16*)alloc((size_t)HIDDEN * DIM * 2);
    bf16* w3t  = (bf16*)alloc((size_t)HIDDEN * DIM * 2);
    bf16* w2t  = (bf16*)alloc((size_t)DIM * HIDDEN * 2);
    bf16* xbuf = (bf16*)alloc((size_t)SEQ * DIM * 2);
    bf16* qkv  = (bf16*)alloc((size_t)SEQ * QKVN * 2);
    float* h   = (float*)alloc((size_t)SEQ * DIM * 4);
    bf16* t1   = (bf16*)alloc((size_t)SEQ * HIDDEN * 2);
    float* Opart = (float*)alloc((size_t)NHEAD * NCHUNK_TOT * 64 * 128 * 4);
    float* Mpart = (float*)alloc((size_t)NHEAD * NCHUNK_TOT * 128 * 4);

    dim3 blk(256);

    cvt_t_kernel<<<dim3(DIM / 64, DIM / 64), blk, 0, stream>>>(wq, qkvt, DIM, DIM);
    cvt_t_kernel<<<dim3(DIM / 64, DIM / 64), blk, 0, stream>>>(wk, qkvt + (size_t)DIM * DIM, DIM, DIM);
    cvt_t_kernel<<<dim3(DIM / 64, DIM / 64), blk, 0, stream>>>(wv, qkvt + (size_t)2 * DIM * DIM, DIM, DIM);
    cvt_t_kernel<<<dim3(DIM / 64, DIM / 64), blk, 0, stream>>>(wo, wot, DIM, DIM);
    cvt_t_kernel<<<dim3(HIDDEN / 64, DIM / 64), blk, 0, stream>>>(w1, w1t, DIM, HIDDEN);
    cvt_t_kernel<<<dim3(HIDDEN / 64, DIM / 64), blk, 0, stream>>>(w3, w3t, DIM, HIDDEN);
    cvt_t_kernel<<<dim3(DIM / 64, HIDDEN / 64), blk, 0, stream>>>(w2, w2t, HIDDEN, DIM);

    rmsnorm_kernel<<<SEQ, blk, 0, stream>>>(x, g_attn, xbuf);
    gemm_bf16<0><<<dim3(QKVN / 128, SEQ / 128), blk, 0, stream>>>(xbuf, qkvt, qkv, nullptr, DIM, QKVN);
    rope_kernel<<<(SEQ * NHEAD * HD / 2) / 256, blk, 0, stream>>>(qkv, f_cos, f_sin);
    flash_attn_chunk<<<dim3(NCHUNK_TOT, NHEAD), blk, 0, stream>>>(qkv, Opart, Mpart);
    attn_combine<<<dim3(SEQ / 64, NHEAD), blk, 0, stream>>>(Opart, Mpart, xbuf);
    gemm_bf16<1><<<dim3(DIM / 128, SEQ / 128), blk, 0, stream>>>(xbuf, wot, h, x, DIM, DIM);
    rmsnorm_kernel<<<SEQ, blk, 0, stream>>>(h, g_ffn, xbuf);
    gemm_bf16<2><<<dim3(HIDDEN / 128, SEQ / 128), blk, 0, stream>>>(xbuf, w1t, t1, nullptr, DIM, HIDDEN);
    gemm_bf16<3><<<dim3(HIDDEN / 128, SEQ / 128), blk, 0, stream>>>(xbuf, w3t, t1, nullptr, DIM, HIDDEN);
    gemm_bf16<1><<<dim3(DIM / 128, SEQ / 128), blk, 0, stream>>>(t1, w2t, out, h, HIDDEN, DIM);
}

// Round 4
// 743.479 us; speedup vs baseline: 1.0319x; 1.0319x over previous
//
#include <hip/hip_runtime.h>
#include <hip/hip_bf16.h>
#include <math.h>

#define SEQ 2048
#define DIM 2048
#define NHEAD 16
#define HD 128
#define HIDDEN 5632
#define QKVN 6144
#define NCHUNK_TOT 80   // sum_{it=0}^{31} (it/8 + 1)
constexpr float EPS = 1e-6f;

typedef __hip_bfloat16 bf16;
using short8  = __attribute__((ext_vector_type(8))) short;
using short4v = __attribute__((ext_vector_type(4))) short;
using floatx4 = __attribute__((ext_vector_type(4))) float;

__device__ inline void gl_lds16(const void* g, void* l) {
    __builtin_amdgcn_global_load_lds((const __attribute__((address_space(1))) void*)g,
                                     (__attribute__((address_space(3))) void*)l, 16, 0, 0);
}

__device__ inline short bfbits(float f) {
    bf16 b = __float2bfloat16(f);
    return *(const short*)&b;
}

// ---------------------------------------------------------------- rmsnorm (f32 in, bf16 out)
__global__ __launch_bounds__(256) void rmsnorm_kernel(const float* __restrict__ x,
                                                      const float* __restrict__ g,
                                                      bf16* __restrict__ out) {
    int row = blockIdx.x;
    const float4* xr = (const float4*)(x + (size_t)row * DIM);
    const float4* g4 = (const float4*)g;
    float4 v[2];
    float ss = 0.f;
#pragma unroll
    for (int i = 0; i < 2; ++i) {
        v[i] = xr[threadIdx.x + 256 * i];
        ss += v[i].x * v[i].x + v[i].y * v[i].y + v[i].z * v[i].z + v[i].w * v[i].w;
    }
    __shared__ float red[256];
    red[threadIdx.x] = ss;
    __syncthreads();
    for (int s = 128; s > 0; s >>= 1) {
        if (threadIdx.x < s) red[threadIdx.x] += red[threadIdx.x + s];
        __syncthreads();
    }
    float scale = rsqrtf(red[0] / (float)DIM + EPS);
    bf16* orow = out + (size_t)row * DIM;
#pragma unroll
    for (int i = 0; i < 2; ++i) {
        float4 gv = g4[threadIdx.x + 256 * i];
        short4v o;
        o[0] = bfbits(v[i].x * scale * gv.x);
        o[1] = bfbits(v[i].y * scale * gv.y);
        o[2] = bfbits(v[i].z * scale * gv.z);
        o[3] = bfbits(v[i].w * scale * gv.w);
        *(short4v*)&orow[(threadIdx.x + 256 * i) * 4] = o;
    }
}

// ---------------------------------------------------------------- weight cast+transpose
// in: [K][N] f32, out: [N][K] bf16.  64x64 tile, float4 loads, 4x4 register
// transpose -> LDS [n][k], short8 (16B) stores.
__global__ __launch_bounds__(256) void cvt_t_kernel(const float* __restrict__ in,
                                                    bf16* __restrict__ out,
                                                    int K, int N) {
    __shared__ bf16 L[64][72];
    const int nb = blockIdx.x * 64, kb = blockIdx.y * 64;
    const int t = threadIdx.x;
    const int nq = t & 15;   // n group of 4
    const int kq = t >> 4;   // k group of 4
    float4 v[4];
#pragma unroll
    for (int i = 0; i < 4; ++i)
        v[i] = *(const float4*)&in[(size_t)(kb + kq * 4 + i) * N + nb + nq * 4];
#pragma unroll
    for (int j = 0; j < 4; ++j) {
        short4v o;
#pragma unroll
        for (int i = 0; i < 4; ++i)
            o[i] = bfbits(((const float*)&v[i])[j]);
        *(short4v*)&L[nq * 4 + j][kq * 4] = o;
    }
    __syncthreads();
    const int c8 = t & 7, rw = t >> 3;
#pragma unroll
    for (int p = 0; p < 2; ++p) {
        int row = rw + p * 32;
        *(short8*)&out[(size_t)(nb + row) * K + kb + c8 * 8] = *(const short8*)&L[row][c8 * 8];
    }
}

// ---------------------------------------------------------------- bf16 MFMA GEMM
// m97 fragment layout + 2-phase double-buffered prefetch (round-2 proven):
// prefetch next K-tile into buf^1 BEFORE ds_read+MFMA on buf, ONE
// __syncthreads per K-step. LDS 32 KB -> 5 blocks/CU. Bijective XCD swizzle.
template <int MODE>
__global__ __launch_bounds__(256) void gemm_bf16(const bf16* __restrict__ A,
                                                 const bf16* __restrict__ Bt,
                                                 void* __restrict__ Cv,
                                                 const float* __restrict__ R,
                                                 int K, int ldc) {
    __shared__ bf16 Asm[2][128 * 32];
    __shared__ bf16 Bsm[2][128 * 32];
    const int t = threadIdx.x;

    // XCD-aware bijective block swizzle
    int wg = blockIdx.y * gridDim.x + blockIdx.x;
    {
        const int nwg = gridDim.x * gridDim.y;
        const int q = nwg >> 3, r = nwg & 7;
        const int xcd = wg & 7, loc = wg >> 3;
        wg = (xcd < r ? xcd * (q + 1) : r * (q + 1) + (xcd - r) * q) + loc;
    }
    const int m0 = (wg / gridDim.x) * 128;
    const int n0 = (wg % gridDim.x) * 128;

    const int lane = t & 63;
    const int wave = t >> 6;
    const int wr = wave >> 1, wc = wave & 1;
    const int quad = lane >> 4;
    const int l16 = lane & 15;

    floatx4 acc[4][4] = {};

    const int ar = t >> 2;
    const int ak = (t & 3) * 8;
    const bf16* Ag = A + (size_t)(m0 + ar) * K + ak;
    const bf16* Bg = Bt + (size_t)(n0 + ar) * K + ak;
    const size_t half = (size_t)64 * K;

    // prologue: stage K-tile 0 into buf 0
    gl_lds16(Ag, Asm[0] + t * 8);
    gl_lds16(Ag + half, Asm[0] + t * 8 + 64 * 32);
    gl_lds16(Bg, Bsm[0] + t * 8);
    gl_lds16(Bg + half, Bsm[0] + t * 8 + 64 * 32);
    __syncthreads();

    int cur = 0;
    for (int k0 = 0; k0 < K; k0 += 32) {
        // issue next-tile prefetch into the other buffer (overlaps with MFMA below)
        if (k0 + 32 < K) {
            const int nb = cur ^ 1;
            gl_lds16(Ag + k0 + 32, Asm[nb] + t * 8);
            gl_lds16(Ag + k0 + 32 + half, Asm[nb] + t * 8 + 64 * 32);
            gl_lds16(Bg + k0 + 32, Bsm[nb] + t * 8);
            gl_lds16(Bg + k0 + 32 + half, Bsm[nb] + t * 8 + 64 * 32);
        }

        const bf16* As = Asm[cur];
        const bf16* Bs = Bsm[cur];
        short8 af[4], bfr[4];
#pragma unroll
        for (int i = 0; i < 4; ++i)
            af[i] = *(const short8*)(As + (wr * 64 + i * 16 + l16) * 32 + quad * 8);
#pragma unroll
        for (int j = 0; j < 4; ++j)
            bfr[j] = *(const short8*)(Bs + (wc * 64 + j * 16 + l16) * 32 + quad * 8);
#pragma unroll
        for (int i = 0; i < 4; ++i)
#pragma unroll
            for (int j = 0; j < 4; ++j)
                acc[i][j] = __builtin_amdgcn_mfma_f32_16x16x32_bf16(af[i], bfr[j], acc[i][j], 0, 0, 0);

        __syncthreads();   // drains vmcnt (prefetch done) + lgkm (reads done)
        cur ^= 1;
    }

#pragma unroll
    for (int i = 0; i < 4; ++i) {
#pragma unroll
        for (int j = 0; j < 4; ++j) {
#pragma unroll
            for (int r = 0; r < 4; ++r) {
                int m = m0 + wr * 64 + i * 16 + quad * 4 + r;
                int n = n0 + wc * 64 + j * 16 + l16;
                size_t idx = (size_t)m * ldc + n;
                float v = acc[i][j][r];
                if (MODE == 0) {
                    ((bf16*)Cv)[idx] = __float2bfloat16(v);
                } else {
                    ((float*)Cv)[idx] = v + R[idx];
                }
            }
        }
    }
}

// ---------------------------------------------------------------- fused W1/W3 SwiGLU GEMM
// One block computes the SAME 128x128 tile of (A@W1t^T) and (A@W3t^T):
// A staged ONCE per K-step, two B streams, 32 MFMA/K-step (2x MFMA per staged
// A byte vs separate passes). Epilogue writes bf16 silu(v1)*v3 directly —
// removes the separate MODE-2 pass + MODE-3 read-modify-write pass.
// LDS 48 KB; acc 2x16 floatx4 -> high VGPR, cap at 2 blocks/CU.
__global__ __launch_bounds__(256, 2) void gemm_w13(const bf16* __restrict__ A,
                                                   const bf16* __restrict__ B1t,
                                                   const bf16* __restrict__ B3t,
                                                   bf16* __restrict__ C,
                                                   int K, int ldc) {
    __shared__ bf16 Asm[2][128 * 32];
    __shared__ bf16 B1s[2][128 * 32];
    __shared__ bf16 B3s[2][128 * 32];
    const int t = threadIdx.x;

    int wg = blockIdx.y * gridDim.x + blockIdx.x;
    {
        const int nwg = gridDim.x * gridDim.y;
        const int q = nwg >> 3, r = nwg & 7;
        const int xcd = wg & 7, loc = wg >> 3;
        wg = (xcd < r ? xcd * (q + 1) : r * (q + 1) + (xcd - r) * q) + loc;
    }
    const int m0 = (wg / gridDim.x) * 128;
    const int n0 = (wg % gridDim.x) * 128;

    const int lane = t & 63;
    const int wave = t >> 6;
    const int wr = wave >> 1, wc = wave & 1;
    const int quad = lane >> 4;
    const int l16 = lane & 15;

    floatx4 acc1[4][4] = {};
    floatx4 acc3[4][4] = {};

    const int ar = t >> 2;
    const int ak = (t & 3) * 8;
    const bf16* Ag  = A   + (size_t)(m0 + ar) * K + ak;
    const bf16* B1g = B1t + (size_t)(n0 + ar) * K + ak;
    const bf16* B3g = B3t + (size_t)(n0 + ar) * K + ak;
    const size_t half = (size_t)64 * K;

    auto stage = [&](int k, int buf) {
        gl_lds16(Ag + k, Asm[buf] + t * 8);
        gl_lds16(Ag + k + half, Asm[buf] + t * 8 + 64 * 32);
        gl_lds16(B1g + k, B1s[buf] + t * 8);
        gl_lds16(B1g + k + half, B1s[buf] + t * 8 + 64 * 32);
        gl_lds16(B3g + k, B3s[buf] + t * 8);
        gl_lds16(B3g + k + half, B3s[buf] + t * 8 + 64 * 32);
    };

    stage(0, 0);
    __syncthreads();

    int cur = 0;
    for (int k0 = 0; k0 < K; k0 += 32) {
        if (k0 + 32 < K) stage(k0 + 32, cur ^ 1);

        const bf16* As = Asm[cur];
        short8 af[4], bfr[4];
#pragma unroll
        for (int i = 0; i < 4; ++i)
            af[i] = *(const short8*)(As + (wr * 64 + i * 16 + l16) * 32 + quad * 8);

        const bf16* B1 = B1s[cur];
#pragma unroll
        for (int j = 0; j < 4; ++j)
            bfr[j] = *(const short8*)(B1 + (wc * 64 + j * 16 + l16) * 32 + quad * 8);
#pragma unroll
        for (int i = 0; i < 4; ++i)
#pragma unroll
            for (int j = 0; j < 4; ++j)
                acc1[i][j] = __builtin_amdgcn_mfma_f32_16x16x32_bf16(af[i], bfr[j], acc1[i][j], 0, 0, 0);

        const bf16* B3 = B3s[cur];
#pragma unroll
        for (int j = 0; j < 4; ++j)
            bfr[j] = *(const short8*)(B3 + (wc * 64 + j * 16 + l16) * 32 + quad * 8);
#pragma unroll
        for (int i = 0; i < 4; ++i)
#pragma unroll
            for (int j = 0; j < 4; ++j)
                acc3[i][j] = __builtin_amdgcn_mfma_f32_16x16x32_bf16(af[i], bfr[j], acc3[i][j], 0, 0, 0);

        __syncthreads();
        cur ^= 1;
    }

#pragma unroll
    for (int i = 0; i < 4; ++i) {
#pragma unroll
        for (int j = 0; j < 4; ++j) {
#pragma unroll
            for (int r = 0; r < 4; ++r) {
                int m = m0 + wr * 64 + i * 16 + quad * 4 + r;
                int n = n0 + wc * 64 + j * 16 + l16;
                float v1 = acc1[i][j][r];
                float v3 = acc3[i][j][r];
                float s = v1 / (1.f + __expf(-v1));
                C[(size_t)m * ldc + n] = __float2bfloat16(s * v3);
            }
        }
    }
}

// ---------------------------------------------------------------- RoPE (in-place, bf16 qkv buffer)
__global__ __launch_bounds__(256) void rope_kernel(bf16* __restrict__ qkv,
                                                   const float* __restrict__ cs,
                                                   const float* __restrict__ sn) {
    int idx = blockIdx.x * 256 + threadIdx.x;
    int d2 = idx % (HD / 2);
    int rest = idx / (HD / 2);
    int h = rest % NHEAD;
    int s = rest / NHEAD;
    float c = cs[s * (HD / 2) + d2];
    float si = sn[s * (HD / 2) + d2];
    bf16* qp = qkv + (size_t)s * QKVN + h * HD + 2 * d2;
    bf16* kp = qp + DIM;
    float qr = __bfloat162float(qp[0]), qi = __bfloat162float(qp[1]);
    qp[0] = __float2bfloat16(qr * c - qi * si);
    qp[1] = __float2bfloat16(qr * si + qi * c);
    float kr = __bfloat162float(kp[0]), ki = __bfloat162float(kp[1]);
    kp[0] = __float2bfloat16(kr * c - ki * si);
    kp[1] = __float2bfloat16(kr * si + ki * c);
}

// ---------------------------------------------------------------- chunked MFMA flash attention
// Grid (80, NHEAD). blockIdx.x decodes to (it = q-tile, c = KV chunk of <=8
// tiles). 1280 uniform blocks; each writes UNNORMALIZED partial O + per-row
// (m, l) in the exp2 domain; attn_combine merges <=4 partials.
__global__ __launch_bounds__(256, 3) void flash_attn_chunk(const bf16* __restrict__ qkv,
                                                           float* __restrict__ Opart,
                                                           float* __restrict__ Mpart) {
    __shared__ bf16 Ks[64][136];    // key-major, pad 8 (stride 272 B)
    __shared__ bf16 Vt[128][72];    // dim-major, pad 8 (stride 144 B)
    __shared__ bf16 Ps[64][72];

    const int h = blockIdx.y;
    int rem = blockIdx.x, it = 0;
    for (;;) { int nc = (it >> 3) + 1; if (rem < nc) break; rem -= nc; ++it; }
    const int c = rem;
    const int q8 = it >> 3, r8 = it & 7;
    const int slot = h * NCHUNK_TOT + (q8 + 1) * (4 * q8 + r8) + c;
    const int j0 = c * 8;
    const int j1 = (j0 + 8 < it + 1) ? (j0 + 8) : (it + 1);

    const int t = threadIdx.x;
    const int lane = t & 63;
    const int w = t >> 6;
    const int quad = lane >> 4;
    const int l16 = lane & 15;
    const int s0 = it * 64;
    // 1/sqrt(128) * log2(e): base-2 softmax
    const float sl2 = (float)(0.08838834764831845 * 1.4426950408889634);

    // ---- Q strip in registers: A-frag layout m=l16, k=quad*8+j
    short8 qreg[4];
    {
        const bf16* qrow = qkv + (size_t)(s0 + 16 * w + l16) * QKVN + h * HD + quad * 8;
#pragma unroll
        for (int ks = 0; ks < 4; ++ks)
            qreg[ks] = *(const short8*)(qrow + ks * 32);
    }

    floatx4 O[8] = {};
    float m_i[4], l_i[4];
#pragma unroll
    for (int r = 0; r < 4; ++r) { m_i[r] = -INFINITY; l_i[r] = 0.f; }

    const int vkg = t >> 5;
    const int vdg = t & 31;

    for (int jt = j0; jt < j1; ++jt) {
        const int tb = jt * 64;
        __syncthreads();

        // ---- stage K tile [64][128], coalesced 16B
#pragma unroll
        for (int u = 0; u < 4; ++u) {
            int vv = t + 256 * u;
            int kr = vv >> 4, kc = vv & 15;
            *(uint4*)&Ks[kr][kc * 8] =
                *(const uint4*)(qkv + (size_t)(tb + kr) * QKVN + DIM + h * HD + kc * 8);
        }
        // ---- stage V transposed via register transpose
        {
            short4v vr[8];
#pragma unroll
            for (int kk = 0; kk < 8; ++kk)
                vr[kk] = *(const short4v*)(qkv + (size_t)(tb + vkg * 8 + kk) * QKVN + 2 * DIM + h * HD + vdg * 4);
#pragma unroll
            for (int dd = 0; dd < 4; ++dd) {
                short8 wv;
#pragma unroll
                for (int kk = 0; kk < 8; ++kk) wv[kk] = vr[kk][dd];
                *(short8*)&Vt[vdg * 4 + dd][vkg * 8] = wv;
            }
        }
        __syncthreads();

        // ---- S = Q K^T : wave strip 16 x 64
        floatx4 sacc[4] = {};
#pragma unroll
        for (int ks = 0; ks < 4; ++ks) {
            short8 kb[4];
#pragma unroll
            for (int nt = 0; nt < 4; ++nt)
                kb[nt] = *(const short8*)&Ks[nt * 16 + l16][ks * 32 + quad * 8];
#pragma unroll
            for (int nt = 0; nt < 4; ++nt)
                sacc[nt] = __builtin_amdgcn_mfma_f32_16x16x32_bf16(qreg[ks], kb[nt], sacc[nt], 0, 0, 0);
        }

        // ---- scale(log2) + causal mask + online softmax, base-2
        float alpha[4];
#pragma unroll
        for (int r = 0; r < 4; ++r) {
            float mx = -INFINITY;
#pragma unroll
            for (int nt = 0; nt < 4; ++nt) {
                float s = sacc[nt][r] * sl2;
                if (jt == it && (nt * 16 + l16) > (16 * w + quad * 4 + r)) s = -INFINITY;
                sacc[nt][r] = s;
                mx = fmaxf(mx, s);
            }
#pragma unroll
            for (int off = 1; off < 16; off <<= 1)
                mx = fmaxf(mx, __shfl_xor(mx, off, 64));
            float mn = fmaxf(m_i[r], mx);
            alpha[r] = exp2f(m_i[r] - mn);
            float lsum = 0.f;
#pragma unroll
            for (int nt = 0; nt < 4; ++nt) {
                float e = exp2f(sacc[nt][r] - mn);
                sacc[nt][r] = e;
                lsum += e;
            }
#pragma unroll
            for (int off = 1; off < 16; off <<= 1)
                lsum += __shfl_xor(lsum, off, 64);
            l_i[r] = l_i[r] * alpha[r] + lsum;
            m_i[r] = mn;
        }

        // ---- P (C-layout) -> LDS, own strip only
#pragma unroll
        for (int nt = 0; nt < 4; ++nt)
#pragma unroll
            for (int r = 0; r < 4; ++r)
                Ps[16 * w + quad * 4 + r][nt * 16 + l16] = __float2bfloat16(sacc[nt][r]);

        // ---- rescale O, then O += P V
#pragma unroll
        for (int nt = 0; nt < 8; ++nt)
#pragma unroll
            for (int r = 0; r < 4; ++r)
                O[nt][r] *= alpha[r];

#pragma unroll
        for (int ks = 0; ks < 2; ++ks) {
            short8 pa = *(const short8*)&Ps[16 * w + l16][ks * 32 + quad * 8];
#pragma unroll
            for (int nt = 0; nt < 8; ++nt) {
                short8 vb = *(const short8*)&Vt[nt * 16 + l16][ks * 32 + quad * 8];
                O[nt] = __builtin_amdgcn_mfma_f32_16x16x32_bf16(pa, vb, O[nt], 0, 0, 0);
            }
        }
    }

    // ---- write UNNORMALIZED partials + (m, l)
    float* Op = Opart + (size_t)slot * (64 * 128);
    float* Mp = Mpart + (size_t)slot * 128;
    if (l16 == 0) {
#pragma unroll
        for (int r = 0; r < 4; ++r) {
            int row = 16 * w + quad * 4 + r;
            Mp[row] = m_i[r];
            Mp[64 + row] = l_i[r];
        }
    }
#pragma unroll
    for (int r = 0; r < 4; ++r) {
        int row = 16 * w + quad * 4 + r;
#pragma unroll
        for (int nt = 0; nt < 8; ++nt)
            Op[row * 128 + nt * 16 + l16] = O[nt][r];
    }
}

// ---------------------------------------------------------------- combine partials -> bf16 out
// Grid (SEQ/64, NHEAD), 256 thr. Thread t: row = t>>2, dim quarter = t&3.
__global__ __launch_bounds__(256) void attn_combine(const float* __restrict__ Opart,
                                                    const float* __restrict__ Mpart,
                                                    bf16* __restrict__ out) {
    const int it = blockIdx.x;
    const int h = blockIdx.y;
    const int nch = (it >> 3) + 1;
    const int q8 = it >> 3, r8 = it & 7;
    const int base = h * NCHUNK_TOT + (q8 + 1) * (4 * q8 + r8);
    const int t = threadIdx.x;
    const int row = t >> 2;
    const int dq = t & 3;

    float mv[4], wgt[4];
    float M = -INFINITY;
#pragma unroll
    for (int c = 0; c < 4; ++c) {
        if (c < nch) {
            mv[c] = Mpart[(size_t)(base + c) * 128 + row];
            M = fmaxf(M, mv[c]);
        }
    }
    float L = 0.f;
#pragma unroll
    for (int c = 0; c < 4; ++c) {
        if (c < nch) {
            wgt[c] = exp2f(mv[c] - M);
            L += Mpart[(size_t)(base + c) * 128 + 64 + row] * wgt[c];
        }
    }
    float inv = 1.f / L;

    float acc[32] = {};
#pragma unroll
    for (int c = 0; c < 4; ++c) {
        if (c < nch) {
            const float* Oc = Opart + ((size_t)(base + c) * 64 + row) * 128 + dq * 32;
            float wc = wgt[c];
#pragma unroll
            for (int k = 0; k < 8; ++k) {
                float4 v = *(const float4*)&Oc[k * 4];
                acc[k * 4 + 0] += wc * v.x;
                acc[k * 4 + 1] += wc * v.y;
                acc[k * 4 + 2] += wc * v.z;
                acc[k * 4 + 3] += wc * v.w;
            }
        }
    }

    bf16* orow = out + (size_t)(it * 64 + row) * DIM + h * HD + dq * 32;
#pragma unroll
    for (int k2 = 0; k2 < 4; ++k2) {
        short8 pk;
#pragma unroll
        for (int e = 0; e < 8; ++e)
            pk[e] = bfbits(acc[k2 * 8 + e] * inv);
        *(short8*)&orow[k2 * 8] = pk;
    }
}

// ---------------------------------------------------------------- launch
extern "C" void kernel_launch(void* const* d_in, const int* in_sizes, int n_in,
                              void* d_out, int out_size, void* d_ws, size_t ws_size,
                              hipStream_t stream) {
    const float* x      = (const float*)d_in[0];
    const float* f_cos  = (const float*)d_in[1];
    const float* f_sin  = (const float*)d_in[2];
    // d_in[3] = mask : ignored (causality analytic)
    const float* wq     = (const float*)d_in[4];
    const float* wk     = (const float*)d_in[5];
    const float* wv     = (const float*)d_in[6];
    const float* wo     = (const float*)d_in[7];
    const float* w1     = (const float*)d_in[8];
    const float* w2     = (const float*)d_in[9];
    const float* w3     = (const float*)d_in[10];
    const float* g_attn = (const float*)d_in[11];
    const float* g_ffn  = (const float*)d_in[12];
    float* out = (float*)d_out;

    char* base = (char*)d_ws;
    size_t off = 0;
    auto alloc = [&](size_t bytes) { void* p = base + off; off += (bytes + 255) & ~255ULL; return p; };
    bf16* qkvt = (bf16*)alloc((size_t)QKVN * DIM * 2);
    bf16* wot  = (bf16*)alloc((size_t)DIM * DIM * 2);
    bf16* w1t  = (bf16*)alloc((size_t)HIDDEN * DIM * 2);
    bf16* w3t  = (bf16*)alloc((size_t)HIDDEN * DIM * 2);
    bf16* w2t  = (bf16*)alloc((size_t)DIM * HIDDEN * 2);
    bf16* xbuf = (bf16*)alloc((size_t)SEQ * DIM * 2);
    bf16* qkv  = (bf16*)alloc((size_t)SEQ * QKVN * 2);
    float* h   = (float*)alloc((size_t)SEQ * DIM * 4);
    bf16* t1   = (bf16*)alloc((size_t)SEQ * HIDDEN * 2);
    float* Opart = (float*)alloc((size_t)NHEAD * NCHUNK_TOT * 64 * 128 * 4);
    float* Mpart = (float*)alloc((size_t)NHEAD * NCHUNK_TOT * 128 * 4);

    dim3 blk(256);

    cvt_t_kernel<<<dim3(DIM / 64, DIM / 64), blk, 0, stream>>>(wq, qkvt, DIM, DIM);
    cvt_t_kernel<<<dim3(DIM / 64, DIM / 64), blk, 0, stream>>>(wk, qkvt + (size_t)DIM * DIM, DIM, DIM);
    cvt_t_kernel<<<dim3(DIM / 64, DIM / 64), blk, 0, stream>>>(wv, qkvt + (size_t)2 * DIM * DIM, DIM, DIM);
    cvt_t_kernel<<<dim3(DIM / 64, DIM / 64), blk, 0, stream>>>(wo, wot, DIM, DIM);
    cvt_t_kernel<<<dim3(HIDDEN / 64, DIM / 64), blk, 0, stream>>>(w1, w1t, DIM, HIDDEN);
    cvt_t_kernel<<<dim3(HIDDEN / 64, DIM / 64), blk, 0, stream>>>(w3, w3t, DIM, HIDDEN);
    cvt_t_kernel<<<dim3(DIM / 64, HIDDEN / 64), blk, 0, stream>>>(w2, w2t, HIDDEN, DIM);

    rmsnorm_kernel<<<SEQ, blk, 0, stream>>>(x, g_attn, xbuf);
    gemm_bf16<0><<<dim3(QKVN / 128, SEQ / 128), blk, 0, stream>>>(xbuf, qkvt, qkv, nullptr, DIM, QKVN);
    rope_kernel<<<(SEQ * NHEAD * HD / 2) / 256, blk, 0, stream>>>(qkv, f_cos, f_sin);
    flash_attn_chunk<<<dim3(NCHUNK_TOT, NHEAD), blk, 0, stream>>>(qkv, Opart, Mpart);
    attn_combine<<<dim3(SEQ / 64, NHEAD), blk, 0, stream>>>(Opart, Mpart, xbuf);
    gemm_bf16<1><<<dim3(DIM / 128, SEQ / 128), blk, 0, stream>>>(xbuf, wot, h, x, DIM, DIM);
    rmsnorm_kernel<<<SEQ, blk, 0, stream>>>(h, g_ffn, xbuf);
    gemm_w13<<<dim3(HIDDEN / 128, SEQ / 128), blk, 0, stream>>>(xbuf, w1t, w3t, t1, DIM, HIDDEN);
    gemm_bf16<1><<<dim3(DIM / 128, SEQ / 128), blk, 0, stream>>>(t1, w2t, out, h, HIDDEN, DIM);
}